// Round 1
// baseline (169.606 us; speedup 1.0000x reference)
//
#include <hip/hip_runtime.h>
#include <math.h>

#define BATCH 32
#define CH    3
#define H     512
#define W     512
#define KWIN  15
#define PAD   7
#define TROWS 8   // output rows per thread in vertical pass

// Pass 1: channel-min + horizontal 15-wide min. One block per (b, row).
__global__ __launch_bounds__(256) void dark_hmin(const float* __restrict__ I,
                                                 float* __restrict__ tmp) {
    const int bh = blockIdx.x;       // b*H + h
    const int b  = bh >> 9;          // / 512
    const int h  = bh & (H - 1);
    const int t  = threadIdx.x;

    __shared__ float s[W + 2 * PAD];

    const float* row0 = I + ((size_t)(b * CH + 0) * H + h) * W;
    const float* row1 = I + ((size_t)(b * CH + 1) * H + h) * W;
    const float* row2 = I + ((size_t)(b * CH + 2) * H + h) * W;

    const int x = t * 2;
    float2 a0 = *(const float2*)(row0 + x);
    float2 a1 = *(const float2*)(row1 + x);
    float2 a2 = *(const float2*)(row2 + x);
    s[PAD + x]     = fminf(fminf(a0.x, a1.x), a2.x);
    s[PAD + x + 1] = fminf(fminf(a0.y, a1.y), a2.y);
    if (t < PAD) {                      // +inf halo (torch pads max_pool with -inf)
        s[t]           = INFINITY;
        s[PAD + W + t] = INFINITY;
    }
    __syncthreads();

    // output x window = dark[x-7 .. x+7] = s[x .. x+14]; output x+1 = s[x+1 .. x+15]
    float common = s[x + 1];
    #pragma unroll
    for (int j = 2; j < KWIN; ++j) common = fminf(common, s[x + j]);
    float m0 = fminf(common, s[x]);
    float m1 = fminf(common, s[x + KWIN]);

    float2 o; o.x = m0; o.y = m1;
    *(float2*)(tmp + ((size_t)b * H + h) * W + x) = o;
}

// Pass 2: vertical 15-tall min. Thread = one column x, TROWS output rows.
__global__ __launch_bounds__(256) void vmin(const float* __restrict__ tmp,
                                            float* __restrict__ out) {
    const int x  = blockIdx.x * 256 + threadIdx.x;   // 0..511
    const int y0 = blockIdx.y * TROWS;
    const int b  = blockIdx.z;

    const float* col = tmp + (size_t)b * H * W + x;

    float v[TROWS + KWIN - 1];                       // 22 rows
    #pragma unroll
    for (int i = 0; i < TROWS + KWIN - 1; ++i) {
        const int y = y0 - PAD + i;
        v[i] = (y >= 0 && y < H) ? col[(size_t)y * W] : INFINITY;
    }

    float* o = out + (size_t)b * H * W + x;
    #pragma unroll
    for (int r = 0; r < TROWS; ++r) {
        float m = v[r];
        #pragma unroll
        for (int j = 1; j < KWIN; ++j) m = fminf(m, v[r + j]);
        o[(size_t)(y0 + r) * W] = m;
    }
}

extern "C" void kernel_launch(void* const* d_in, const int* in_sizes, int n_in,
                              void* d_out, int out_size, void* d_ws, size_t ws_size,
                              hipStream_t stream) {
    const float* I   = (const float*)d_in[0];
    // d_in[1] is k == 15, hard-coded (KWIN/PAD)
    float* out = (float*)d_out;
    float* tmp = (float*)d_ws;   // BATCH*H*W floats = 33.6 MB

    dark_hmin<<<dim3(BATCH * H), dim3(256), 0, stream>>>(I, tmp);
    vmin<<<dim3(W / 256, H / TROWS, BATCH), dim3(256), 0, stream>>>(tmp, out);
}